// Round 5
// baseline (204.197 us; speedup 1.0000x reference)
//
#include <hip/hip_runtime.h>

#define BATCH   16384
#define HIDDEN  1024
#define K2      2048     // x | h_prev   (h_mem folded into MQ gather)
#define MEMSZ   1024
#define NBITS   10

#define BM 256
#define BN 256
#define BK 64
#define NT (K2 / BK)     // 32 K-tiles

typedef __bf16 bf16x8 __attribute__((ext_vector_type(8)));
typedef float  f32x4  __attribute__((ext_vector_type(4)));

__device__ __forceinline__ unsigned short f2bf(float f) {
    unsigned int u = __float_as_uint(f);
    u += 0x7FFFu + ((u >> 16) & 1u);   // round-to-nearest-even
    return (unsigned short)(u >> 16);
}

__device__ __forceinline__ void gload_lds16(const void* g, void* l) {
    __builtin_amdgcn_global_load_lds(
        (const __attribute__((address_space(1))) unsigned int*)g,
        (__attribute__((address_space(3))) unsigned int*)l,
        16, 0, 0);
}

// ---------------------------------------------------------------------------
// Pack kernel: Bm[1024][2048] = bf16([W|U]); Mem_bf16 = bf16(memory);
// Q_bf16 = bf16(Q_w).
// ---------------------------------------------------------------------------
__global__ void pack_kernel(const float* __restrict__ W,
                            const float* __restrict__ U,
                            const float* __restrict__ memory,
                            const float* __restrict__ Q,
                            unsigned short* __restrict__ Bm,
                            unsigned short* __restrict__ Mem,
                            unsigned short* __restrict__ Qb) {
    int u = blockIdx.x * 256 + threadIdx.x;
    const float* src;
    unsigned short* dst;
    if (u < 524288) {                       // Bm: [1024][2048]
        int n = u >> 9;
        int k = (u & 511) * 4;
        src = (k < 1024) ? (W + (size_t)n * 1024 + k)
                         : (U + (size_t)n * 1024 + (k - 1024));
        dst = Bm + (size_t)n * K2 + k;
    } else if (u < 786432) {                // Mem_bf16
        int f = (u - 524288) * 4;
        src = memory + f;  dst = Mem + f;
    } else if (u < 1048576) {               // Q_bf16
        int f = (u - 786432) * 4;
        src = Q + f;  dst = Qb + f;
    } else return;
    float4 v = *reinterpret_cast<const float4*>(src);
    ushort4 o;
    o.x = f2bf(v.x); o.y = f2bf(v.y); o.z = f2bf(v.z); o.w = f2bf(v.w);
    *reinterpret_cast<ushort4*>(dst) = o;
}

// ---------------------------------------------------------------------------
// MQ[1024][1024] f32 = Mem_bf16 @ Qb^T, split-K x4, atomicAdd epilogue.
// ---------------------------------------------------------------------------
__global__ __launch_bounds__(256) void mq_kernel(
        const unsigned short* __restrict__ Mem,
        const unsigned short* __restrict__ Qb,
        float* __restrict__ MQ) {
    __shared__ unsigned short As[128 * 64];
    __shared__ unsigned short Bs[128 * 64];

    const int ks = blockIdx.x >> 6;
    const int mb = (blockIdx.x >> 3) & 7;
    const int nb = blockIdx.x & 7;
    const int t    = threadIdx.x;
    const int lane = t & 63;
    const int w    = t >> 6;
    const int wr   = w >> 1, wc = w & 1;
    const int rr   = lane & 15, rq = lane >> 4;
    const int c8   = (t & 7) * 8;
    const int srow = t >> 3;

    f32x4 acc[4][4] = {};

    for (int kt = 0; kt < 4; ++kt) {
        const int k0 = ks * 256 + kt * 64;
#pragma unroll
        for (int i = 0; i < 4; ++i) {
            int r = i * 32 + srow;
            gload_lds16(Mem + (size_t)(mb * 128 + r) * 1024 + k0 + c8, As + i * 2048 + t * 8);
            gload_lds16(Qb  + (size_t)(nb * 128 + r) * 1024 + k0 + c8, Bs + i * 2048 + t * 8);
        }
        __syncthreads();
#pragma unroll
        for (int kk = 0; kk < 2; ++kk) {
            const int krd = kk * 32 + rq * 8;
            bf16x8 af[4], bfv[4];
#pragma unroll
            for (int m = 0; m < 4; ++m)
                af[m] = *reinterpret_cast<const bf16x8*>(As + (wr * 64 + m * 16 + rr) * 64 + krd);
#pragma unroll
            for (int n = 0; n < 4; ++n)
                bfv[n] = *reinterpret_cast<const bf16x8*>(Bs + (wc * 64 + n * 16 + rr) * 64 + krd);
#pragma unroll
            for (int m = 0; m < 4; ++m)
#pragma unroll
                for (int n = 0; n < 4; ++n)
                    acc[m][n] = __builtin_amdgcn_mfma_f32_16x16x32_bf16(
                        af[m], bfv[n], acc[m][n], 0, 0, 0);
        }
        __syncthreads();
    }

#pragma unroll
    for (int m = 0; m < 4; ++m)
#pragma unroll
        for (int n = 0; n < 4; ++n) {
            int gcol = nb * 128 + wc * 64 + n * 16 + rr;
#pragma unroll
            for (int j = 0; j < 4; ++j) {
                int grow = mb * 128 + wr * 64 + m * 16 + rq * 4 + j;
                atomicAdd(&MQ[(size_t)grow * 1024 + gcol], acc[m][n][j]);
            }
        }
}

// ---------------------------------------------------------------------------
// One wave per batch row: fp32 logits (sign-exact) -> memory index only.
// ---------------------------------------------------------------------------
__global__ __launch_bounds__(256) void logits_kernel(
        const float* __restrict__ h_prev,
        const float* __restrict__ M_w,
        const float* __restrict__ M_b,
        int* __restrict__ idxbuf) {
    int row  = (blockIdx.x * blockDim.x + threadIdx.x) >> 6;
    int lane = threadIdx.x & 63;
    if (row >= BATCH) return;

    const float4* hp = reinterpret_cast<const float4*>(h_prev + (size_t)row * HIDDEN);
    float4 hv[4];
#pragma unroll
    for (int i = 0; i < 4; ++i) hv[i] = hp[i * 64 + lane];

    int idx = 0;
#pragma unroll
    for (int j = 0; j < NBITS; ++j) {
        const float4* mp = reinterpret_cast<const float4*>(M_w + (size_t)j * HIDDEN);
        float s = 0.f;
#pragma unroll
        for (int i = 0; i < 4; ++i) {
            float4 m = mp[i * 64 + lane];
            s += hv[i].x * m.x + hv[i].y * m.y + hv[i].z * m.z + hv[i].w * m.w;
        }
#pragma unroll
        for (int off = 32; off >= 1; off >>= 1) s += __shfl_xor(s, off, 64);
        float logit = s + M_b[j];
        if (logit > 0.f) idx |= (1 << (NBITS - 1 - j));
    }
    if (lane == 0) idxbuf[row] = idx;
}

// ---------------------------------------------------------------------------
// Fused 256x256-tile 8-phase GEMM: C = bf16([x|h_prev]) @ Bm^T, f32 accum.
// A is staged in-kernel: ph0 issues 8 global f32 loads (tile kt+2); ph3
// converts + swizzled ds_write_b128 into the region freed by ph2's barrier.
// B staged via global_load_lds as before.  Read schedule 16/0/8/0 (R2/R4).
// ---------------------------------------------------------------------------

__device__ __forceinline__ void stage_g(const unsigned short* __restrict__ src,
                                        int rowbase, int kt, int g,
                                        unsigned short* ldsTile, int t) {
    const int o      = g * 8192 + t * 16;     // byte offset within 32 KB tile
    const int row    = o >> 7;                // 0..255  (128 B per row)
    const int inner  = o & 127;
    const int sinner = inner ^ ((row & 7) << 4);
    const char* gp = reinterpret_cast<const char*>(
                         src + (size_t)(rowbase + row) * K2 + kt * BK) + sinner;
    gload_lds16(gp, reinterpret_cast<char*>(ldsTile) + o);
}

// Issue 8 f32 global loads covering this thread's 4 chunks of one A-tile.
__device__ __forceinline__ void loadA8(const float* __restrict__ base, int arow,
                                       int kloc, int t, float4* va) {
#pragma unroll
    for (int g = 0; g < 4; ++g) {
        const float* p = base + (size_t)(arow + g * 64 + (t >> 3)) * 1024
                              + kloc + (t & 7) * 8;
        va[2 * g]     = *reinterpret_cast<const float4*>(p);
        va[2 * g + 1] = *reinterpret_cast<const float4*>(p + 4);
    }
}

// Convert + write this thread's 4 chunks (swizzled) into an A LDS tile.
__device__ __forceinline__ void writeA(unsigned short* tile, int t,
                                       const float4* va) {
#pragma unroll
    for (int g = 0; g < 4; ++g) {
        bf16x8 v;
#pragma unroll
        for (int e = 0; e < 4; ++e) {
            v[e]     = (__bf16)va[2 * g][e];
            v[4 + e] = (__bf16)va[2 * g + 1][e];
        }
        const int o   = g * 8192 + t * 16;
        const int row = o >> 7;
        const int dst = (o & ~127) | ((o & 127) ^ ((row & 7) << 4));
        *reinterpret_cast<bf16x8*>(reinterpret_cast<char*>(tile) + dst) = v;
    }
}

__device__ __forceinline__ bf16x8 ldsfrag(const unsigned short* tile, int row,
                                          int kbyte_x_sw) {
    return *reinterpret_cast<const bf16x8*>(
        reinterpret_cast<const char*>(tile) + row * 128 + kbyte_x_sw);
}

#define BAR_IN()                                                     \
    do {                                                             \
        asm volatile("" ::: "memory");                               \
        __builtin_amdgcn_s_barrier();                                \
        asm volatile("s_waitcnt lgkmcnt(0)" ::: "memory");           \
        __builtin_amdgcn_sched_barrier(0);                           \
    } while (0)

#define BAR_OUT()                                                    \
    do {                                                             \
        __builtin_amdgcn_sched_barrier(0);                           \
        asm volatile("" ::: "memory");                               \
        __builtin_amdgcn_s_barrier();                                \
    } while (0)

#define MFMA_Q(MB, NB)                                                         \
    {                                                                          \
        __builtin_amdgcn_s_setprio(1);                                         \
        _Pragma("unroll") for (int m_ = 0; m_ < 4; ++m_)                       \
        _Pragma("unroll") for (int n_ = 0; n_ < 2; ++n_)                       \
        _Pragma("unroll") for (int kk_ = 0; kk_ < 2; ++kk_)                    \
            acc[(MB) + m_][(NB) + n_] =                                        \
                __builtin_amdgcn_mfma_f32_16x16x32_bf16(                       \
                    af[m_][kk_], bfr[(NB) + n_][kk_],                          \
                    acc[(MB) + m_][(NB) + n_], 0, 0, 0);                       \
        __builtin_amdgcn_s_setprio(0);                                         \
    }

__global__ __launch_bounds__(512, 2) void gemm_kernel(
        const float* __restrict__ x,
        const float* __restrict__ h_prev,
        const unsigned short* __restrict__ Bm,
        float* __restrict__ C) {
    __shared__ alignas(16) unsigned short lds[2][2][BM * BK];  // 128 KiB

    // Bijective XCD swizzle: each XCD owns 8 mblks x all 4 nblks.
    const int bid  = blockIdx.x;
    const int wgid = (bid & 7) * 32 + (bid >> 3);
    const int mblk = wgid >> 2;           // 0..63
    const int nblk = wgid & 3;            // 0..3

    const int t    = threadIdx.x;
    const int lane = t & 63;
    const int w    = t >> 6;
    const int wr   = w >> 2;              // 0..1  (M)
    const int wc   = w & 3;               // 0..3  (N)
    const int rr   = lane & 15;
    const int rq   = lane >> 4;
    const int sw   = (rr & 7) << 4;
    const int rqb  = rq * 16;
    const int wrb  = wr * 128;
    const int wcb  = wc * 64;

    const int arow = mblk * BM;
    const int brow = nblk * BN;

    f32x4 acc[8][4] = {};
    float4 va[8];

    // ---- prologue: A(0),A(1) via reg-staging; B(0),B(1) via gload_lds -----
    {
        loadA8(x, arow, 0, t, va);                       // kt=0 -> x cols 0-63
#pragma unroll
        for (int g = 0; g < 4; ++g) stage_g(Bm, brow, 0, g, &lds[0][1][0], t);
        asm volatile("s_waitcnt vmcnt(4)" ::: "memory"); // A0 landed
        writeA(&lds[0][0][0], t, va);

        loadA8(x, arow, 64, t, va);                      // kt=1 -> x cols 64-127
#pragma unroll
        for (int g = 0; g < 4; ++g) stage_g(Bm, brow, 1, g, &lds[1][1][0], t);
        asm volatile("s_waitcnt vmcnt(4)" ::: "memory"); // A1 + B0 landed
        writeA(&lds[1][0][0], t, va);

        asm volatile("s_waitcnt lgkmcnt(0)" ::: "memory"); // ds_writes done
        __builtin_amdgcn_s_barrier();
    }

    bf16x8 af[4][2];
    bf16x8 bfr[4][2];

#pragma unroll 2
    for (int kt = 0; kt < NT; ++kt) {
        const int c = kt & 1;
        const unsigned short* At = &lds[c][0][0];
        const unsigned short* Bt = &lds[c][1][0];
        unsigned short* curA = &lds[c][0][0];      // tile kt+2 A target
        unsigned short* curB = &lds[c][1][0];      // tile kt+2 B target
        const bool pf = (kt + 2 < NT);

        // -- phase 0: issue A(kt+2) f32 loads; read af[0-3] + bfr[0-3] ------
        if (pf) {
            const float* abase = (kt + 2 < 16) ? x : h_prev;
            loadA8(abase, arow, ((kt + 2) & 15) * 64, t, va);
        }
#pragma unroll
        for (int m = 0; m < 4; ++m) {
            af[m][0] = ldsfrag(At, wrb + m * 16 + rr, (rqb) ^ sw);
            af[m][1] = ldsfrag(At, wrb + m * 16 + rr, (64 + rqb) ^ sw);
        }
#pragma unroll
        for (int n = 0; n < 4; ++n) {
            bfr[n][0] = ldsfrag(Bt, wcb + n * 16 + rr, (rqb) ^ sw);
            bfr[n][1] = ldsfrag(Bt, wcb + n * 16 + rr, (64 + rqb) ^ sw);
        }
        BAR_IN();
        MFMA_Q(0, 0);          // m0-3 x n0-1
        BAR_OUT();

        // -- phase 1: stall-free MFMA ---------------------------------------
        BAR_IN();
        MFMA_Q(0, 2);          // m0-3 x n2-3
        BAR_OUT();

        // -- phase 2: read af rows 64-127; stage B(kt+2) g0,g1 --------------
#pragma unroll
        for (int m = 0; m < 4; ++m) {
            af[m][0] = ldsfrag(At, wrb + 64 + m * 16 + rr, (rqb) ^ sw);
            af[m][1] = ldsfrag(At, wrb + 64 + m * 16 + rr, (64 + rqb) ^ sw);
        }
        if (pf) {
            stage_g(Bm, brow, kt + 2, 0, curB, t);
            stage_g(Bm, brow, kt + 2, 1, curB, t);
        }
        BAR_IN();
        MFMA_Q(4, 0);          // m4-7 x n0-1
        BAR_OUT();
        // all A reads of buf[c] done across waves -> A region free

        // -- phase 3: stage B(kt+2) g2,g3; cvt + swizzled ds_write A(kt+2) --
        if (pf) {
            stage_g(Bm, brow, kt + 2, 2, curB, t);
            stage_g(Bm, brow, kt + 2, 3, curB, t);
            // allow the 4 B(kt+2) stages to stay in flight; A(kt+2) f32 loads
            // and B(kt+1) (older) are forced complete.
            asm volatile("s_waitcnt vmcnt(4)" ::: "memory");
            writeA(curA, t, va);
        } else if (kt + 1 < NT) {
            asm volatile("s_waitcnt vmcnt(0)" ::: "memory"); // tail drain
        }
        BAR_IN();              // barrier + lgkmcnt(0): ds_writes complete
        MFMA_Q(4, 2);          // m4-7 x n2-3
        __builtin_amdgcn_sched_barrier(0);
        asm volatile("" ::: "memory");
        __builtin_amdgcn_s_barrier();
    }

    // ---- epilogue: C/D layout col=lane&15, row=(lane>>4)*4+j --------------
#pragma unroll
    for (int mi = 0; mi < 8; ++mi) {
#pragma unroll
        for (int n = 0; n < 4; ++n) {
            const int gcol = nblk * BN + wcb + n * 16 + rr;
#pragma unroll
            for (int j = 0; j < 4; ++j) {
                const int grow = mblk * BM + wrb + mi * 16 + rq * 4 + j;
                C[(size_t)grow * HIDDEN + gcol] = acc[mi][n][j];
            }
        }
    }
}

// ---------------------------------------------------------------------------
// In-place: p = C + MQ[idx[row]] + (W_b+U_b+Q_b); LayerNorm; sigmoid.
// ---------------------------------------------------------------------------
__global__ __launch_bounds__(256) void ln_kernel(
        float* __restrict__ C,
        const int* __restrict__ idxbuf,
        const float* __restrict__ MQ,
        const float* __restrict__ W_b, const float* __restrict__ U_b,
        const float* __restrict__ Q_b, const float* __restrict__ ln_g,
        const float* __restrict__ ln_b) {
    const int row = blockIdx.x;
    const int t   = threadIdx.x;
    const int midx = idxbuf[row];
    float4* rowp = reinterpret_cast<float4*>(C + (size_t)row * HIDDEN);
    const float4* mqp = reinterpret_cast<const float4*>(MQ + (size_t)midx * HIDDEN);

    float4 p  = rowp[t];
    float4 mq = mqp[t];
    float4 bw = reinterpret_cast<const float4*>(W_b)[t];
    float4 bu = reinterpret_cast<const float4*>(U_b)[t];
    float4 bq = reinterpret_cast<const float4*>(Q_b)[t];
    p.x += mq.x + bw.x + bu.x + bq.x;
    p.y += mq.y + bw.y + bu.y + bq.y;
    p.z += mq.z + bw.z + bu.z + bq.z;
    p.w += mq.w + bw.w + bu.w + bq.w;

    float s  = p.x + p.y + p.z + p.w;
    float sq = p.x * p.x + p.y * p.y + p.z * p.z + p.w * p.w;
#pragma unroll
    for (int off = 32; off >= 1; off >>= 1) {
        s  += __shfl_xor(s,  off, 64);
        sq += __shfl_xor(sq, off, 64);
    }
    __shared__ float red[8];
    const int lane = t & 63, w = t >> 6;
    if (lane == 0) { red[w] = s; red[4 + w] = sq; }
    __syncthreads();
    const float S    = red[0] + red[1] + red[2] + red[3];
    const float SQ   = red[4] + red[5] + red[6] + red[7];
    const float mean = S * (1.0f / HIDDEN);
    const float var  = SQ * (1.0f / HIDDEN) - mean * mean;
    const float rstd = rsqrtf(var + 1e-5f);

    float4 g = reinterpret_cast<const float4*>(ln_g)[t];
    float4 b = reinterpret_cast<const float4*>(ln_b)[t];
    float4 o;
    o.x = 1.f / (1.f + __expf(-((p.x - mean) * rstd * g.x + b.x)));
    o.y = 1.f / (1.f + __expf(-((p.y - mean) * rstd * g.y + b.y)));
    o.z = 1.f / (1.f + __expf(-((p.z - mean) * rstd * g.z + b.z)));
    o.w = 1.f / (1.f + __expf(-((p.w - mean) * rstd * g.w + b.w)));
    rowp[t] = o;
}

// ---------------------------------------------------------------------------
extern "C" void kernel_launch(void* const* d_in, const int* in_sizes, int n_in,
                              void* d_out, int out_size, void* d_ws, size_t ws_size,
                              hipStream_t stream) {
    const float* x      = (const float*)d_in[0];
    const float* h_prev = (const float*)d_in[1];
    const float* memory = (const float*)d_in[2];
    const float* W_w    = (const float*)d_in[3];
    const float* W_b    = (const float*)d_in[4];
    const float* U_w    = (const float*)d_in[5];
    const float* U_b    = (const float*)d_in[6];
    const float* Q_w    = (const float*)d_in[7];
    const float* Q_b    = (const float*)d_in[8];
    const float* M_w    = (const float*)d_in[9];
    const float* M_b    = (const float*)d_in[10];
    const float* ln_g   = (const float*)d_in[11];
    const float* ln_b   = (const float*)d_in[12];

    // ws layout (bytes):
    char* ws = (char*)d_ws;
    unsigned short* Bm  = (unsigned short*)(ws);                 // 4,194,304
    unsigned short* Mem = (unsigned short*)(ws + 4194304);       // 2,097,152
    unsigned short* Qb  = (unsigned short*)(ws + 6291456);       // 2,097,152
    float*          MQ  = (float*)         (ws + 8388608);       // 4,194,304
    int*            idx = (int*)           (ws + 12582912);      //    65,536
    float* pre = (float*)d_out;

    hipLaunchKernelGGL(pack_kernel, dim3(4096), dim3(256), 0, stream,
                       W_w, U_w, memory, Q_w, Bm, Mem, Qb);
    hipMemsetAsync(MQ, 0, (size_t)MEMSZ * HIDDEN * sizeof(float), stream);
    hipLaunchKernelGGL(mq_kernel, dim3(256), dim3(256), 0, stream,
                       Mem, Qb, MQ);
    hipLaunchKernelGGL(logits_kernel, dim3(BATCH / 4), dim3(256), 0, stream,
                       h_prev, M_w, M_b, idx);
    hipLaunchKernelGGL(gemm_kernel, dim3((BATCH / BM) * (HIDDEN / BN)), dim3(512), 0, stream,
                       x, h_prev, Bm, pre);
    hipLaunchKernelGGL(ln_kernel, dim3(BATCH), dim3(256), 0, stream,
                       pre, idx, MQ, W_b, U_b, Q_b, ln_g, ln_b);
}

// Round 6
// 170.157 us; speedup vs baseline: 1.2000x; 1.2000x over previous
//
#include <hip/hip_runtime.h>

#define BATCH   16384
#define HIDDEN  1024
#define K2      2048     // x | h_prev   (h_mem folded into MQ gather)
#define MEMSZ   1024
#define NBITS   10

#define BM 256
#define BN 256
#define BK 64
#define NT (K2 / BK)     // 32 K-tiles

typedef __bf16 bf16x8 __attribute__((ext_vector_type(8)));
typedef float  f32x4  __attribute__((ext_vector_type(4)));

__device__ __forceinline__ unsigned short f2bf(float f) {
    unsigned int u = __float_as_uint(f);
    u += 0x7FFFu + ((u >> 16) & 1u);   // round-to-nearest-even
    return (unsigned short)(u >> 16);
}

__device__ __forceinline__ void gload_lds16(const void* g, void* l) {
    __builtin_amdgcn_global_load_lds(
        (const __attribute__((address_space(1))) unsigned int*)g,
        (__attribute__((address_space(3))) unsigned int*)l,
        16, 0, 0);
}

// ---------------------------------------------------------------------------
// Pack kernel: Bm[1024][2048] = bf16([W|U]); Mem_bf16 = bf16(memory);
// Q_bf16 = bf16(Q_w).
// ---------------------------------------------------------------------------
__global__ void pack_kernel(const float* __restrict__ W,
                            const float* __restrict__ U,
                            const float* __restrict__ memory,
                            const float* __restrict__ Q,
                            unsigned short* __restrict__ Bm,
                            unsigned short* __restrict__ Mem,
                            unsigned short* __restrict__ Qb) {
    int u = blockIdx.x * 256 + threadIdx.x;
    const float* src;
    unsigned short* dst;
    if (u < 524288) {                       // Bm: [1024][2048]
        int n = u >> 9;
        int k = (u & 511) * 4;
        src = (k < 1024) ? (W + (size_t)n * 1024 + k)
                         : (U + (size_t)n * 1024 + (k - 1024));
        dst = Bm + (size_t)n * K2 + k;
    } else if (u < 786432) {                // Mem_bf16
        int f = (u - 524288) * 4;
        src = memory + f;  dst = Mem + f;
    } else if (u < 1048576) {               // Q_bf16
        int f = (u - 786432) * 4;
        src = Q + f;  dst = Qb + f;
    } else return;
    float4 v = *reinterpret_cast<const float4*>(src);
    ushort4 o;
    o.x = f2bf(v.x); o.y = f2bf(v.y); o.z = f2bf(v.z); o.w = f2bf(v.w);
    *reinterpret_cast<ushort4*>(dst) = o;
}

// ---------------------------------------------------------------------------
// MQ[1024][1024] f32 = Mem_bf16 @ Qb^T, split-K x4, atomicAdd epilogue.
// ---------------------------------------------------------------------------
__global__ __launch_bounds__(256) void mq_kernel(
        const unsigned short* __restrict__ Mem,
        const unsigned short* __restrict__ Qb,
        float* __restrict__ MQ) {
    __shared__ unsigned short As[128 * 64];
    __shared__ unsigned short Bs[128 * 64];

    const int ks = blockIdx.x >> 6;
    const int mb = (blockIdx.x >> 3) & 7;
    const int nb = blockIdx.x & 7;
    const int t    = threadIdx.x;
    const int lane = t & 63;
    const int w    = t >> 6;
    const int wr   = w >> 1, wc = w & 1;
    const int rr   = lane & 15, rq = lane >> 4;
    const int c8   = (t & 7) * 8;
    const int srow = t >> 3;

    f32x4 acc[4][4] = {};

    for (int kt = 0; kt < 4; ++kt) {
        const int k0 = ks * 256 + kt * 64;
#pragma unroll
        for (int i = 0; i < 4; ++i) {
            int r = i * 32 + srow;
            gload_lds16(Mem + (size_t)(mb * 128 + r) * 1024 + k0 + c8, As + i * 2048 + t * 8);
            gload_lds16(Qb  + (size_t)(nb * 128 + r) * 1024 + k0 + c8, Bs + i * 2048 + t * 8);
        }
        __syncthreads();
#pragma unroll
        for (int kk = 0; kk < 2; ++kk) {
            const int krd = kk * 32 + rq * 8;
            bf16x8 af[4], bfv[4];
#pragma unroll
            for (int m = 0; m < 4; ++m)
                af[m] = *reinterpret_cast<const bf16x8*>(As + (wr * 64 + m * 16 + rr) * 64 + krd);
#pragma unroll
            for (int n = 0; n < 4; ++n)
                bfv[n] = *reinterpret_cast<const bf16x8*>(Bs + (wc * 64 + n * 16 + rr) * 64 + krd);
#pragma unroll
            for (int m = 0; m < 4; ++m)
#pragma unroll
                for (int n = 0; n < 4; ++n)
                    acc[m][n] = __builtin_amdgcn_mfma_f32_16x16x32_bf16(
                        af[m], bfv[n], acc[m][n], 0, 0, 0);
        }
        __syncthreads();
    }

#pragma unroll
    for (int m = 0; m < 4; ++m)
#pragma unroll
        for (int n = 0; n < 4; ++n) {
            int gcol = nb * 128 + wc * 64 + n * 16 + rr;
#pragma unroll
            for (int j = 0; j < 4; ++j) {
                int grow = mb * 128 + wr * 64 + m * 16 + rq * 4 + j;
                atomicAdd(&MQ[(size_t)grow * 1024 + gcol], acc[m][n][j]);
            }
        }
}

// ---------------------------------------------------------------------------
// One wave per batch row: fp32 logits (sign-exact) -> idx; emit bf16
// A[row][2048] = [x | h_prev]; write idx[row].
// ---------------------------------------------------------------------------
__global__ __launch_bounds__(256) void build_a_kernel(
        const float* __restrict__ x,
        const float* __restrict__ h_prev,
        const float* __restrict__ M_w,
        const float* __restrict__ M_b,
        unsigned short* __restrict__ A,
        int* __restrict__ idxbuf) {
    int row  = (blockIdx.x * blockDim.x + threadIdx.x) >> 6;
    int lane = threadIdx.x & 63;
    if (row >= BATCH) return;

    const float4* hp = reinterpret_cast<const float4*>(h_prev + (size_t)row * HIDDEN);
    float4 hv[4];
#pragma unroll
    for (int i = 0; i < 4; ++i) hv[i] = hp[i * 64 + lane];

    int idx = 0;
#pragma unroll
    for (int j = 0; j < NBITS; ++j) {
        const float4* mp = reinterpret_cast<const float4*>(M_w + (size_t)j * HIDDEN);
        float s = 0.f;
#pragma unroll
        for (int i = 0; i < 4; ++i) {
            float4 m = mp[i * 64 + lane];
            s += hv[i].x * m.x + hv[i].y * m.y + hv[i].z * m.z + hv[i].w * m.w;
        }
#pragma unroll
        for (int off = 32; off >= 1; off >>= 1) s += __shfl_xor(s, off, 64);
        float logit = s + M_b[j];
        if (logit > 0.f) idx |= (1 << (NBITS - 1 - j));
    }
    if (lane == 0) idxbuf[row] = idx;

    unsigned short* arow = A + (size_t)row * K2;
    const float4* xp = reinterpret_cast<const float4*>(x + (size_t)row * HIDDEN);
#pragma unroll
    for (int i = 0; i < 4; ++i) {
        int off = i * 256 + lane * 4;
        float4 vx = xp[i * 64 + lane];
        ushort4 ox; ox.x = f2bf(vx.x); ox.y = f2bf(vx.y); ox.z = f2bf(vx.z); ox.w = f2bf(vx.w);
        *reinterpret_cast<ushort4*>(arow + off) = ox;

        ushort4 oh; oh.x = f2bf(hv[i].x); oh.y = f2bf(hv[i].y); oh.z = f2bf(hv[i].z); oh.w = f2bf(hv[i].w);
        *reinterpret_cast<ushort4*>(arow + 1024 + off) = oh;
    }
}

// ---------------------------------------------------------------------------
// 256x256-tile 8-phase GEMM, PHASE-ROTATED: reads issued in phase p feed
// phase p+1's MFMA; counted lgkmcnt(N_p) so the LDS pipe services reads
// UNDER the current MFMA block.  Reads/phase 4/8/0/12; stages 2/0/2/4;
// vmcnt(2) at ph2-end guarantees tile kt+1 landed before ph3 pre-reads it.
// ---------------------------------------------------------------------------

__device__ __forceinline__ void stage_g(const unsigned short* __restrict__ src,
                                        int rowbase, int kt, int g,
                                        unsigned short* ldsTile, int t) {
    const int o      = g * 8192 + t * 16;     // byte offset within 32 KB tile
    const int row    = o >> 7;                // 0..255  (128 B per row)
    const int inner  = o & 127;
    const int sinner = inner ^ ((row & 7) << 4);
    const char* gp = reinterpret_cast<const char*>(
                         src + (size_t)(rowbase + row) * K2 + kt * BK) + sinner;
    gload_lds16(gp, reinterpret_cast<char*>(ldsTile) + o);
}

__device__ __forceinline__ bf16x8 ldsfrag(const unsigned short* tile, int row,
                                          int kbyte_x_sw) {
    return *reinterpret_cast<const bf16x8*>(
        reinterpret_cast<const char*>(tile) + row * 128 + kbyte_x_sw);
}

// barrier, then wait only until N newest ds ops remain outstanding
// (rule #18: sched_barrier(0) pins MFMA after the wait).
#define WAIT_PH(N)                                                   \
    do {                                                             \
        asm volatile("" ::: "memory");                               \
        __builtin_amdgcn_s_barrier();                                \
        asm volatile("s_waitcnt lgkmcnt(" #N ")" ::: "memory");      \
        __builtin_amdgcn_sched_barrier(0);                           \
    } while (0)

#define BAR_OUT()                                                    \
    do {                                                             \
        __builtin_amdgcn_sched_barrier(0);                           \
        asm volatile("" ::: "memory");                               \
        __builtin_amdgcn_s_barrier();                                \
    } while (0)

// One C-quadrant x K=64: 16 MFMAs, setprio-wrapped (T5).
#define MFMA_Q(AF, MB, NB)                                                     \
    {                                                                          \
        __builtin_amdgcn_s_setprio(1);                                         \
        _Pragma("unroll") for (int m_ = 0; m_ < 4; ++m_)                       \
        _Pragma("unroll") for (int n_ = 0; n_ < 2; ++n_)                       \
        _Pragma("unroll") for (int kk_ = 0; kk_ < 2; ++kk_)                    \
            acc[(MB) + m_][(NB) + n_] =                                        \
                __builtin_amdgcn_mfma_f32_16x16x32_bf16(                       \
                    AF[m_][kk_], bfr[(NB) + n_][kk_],                          \
                    acc[(MB) + m_][(NB) + n_], 0, 0, 0);                       \
        __builtin_amdgcn_s_setprio(0);                                         \
    }

__global__ __launch_bounds__(512, 2) void gemm_kernel(
        const unsigned short* __restrict__ A,
        const unsigned short* __restrict__ Bm,
        float* __restrict__ C) {
    __shared__ alignas(16) unsigned short lds[2][2][BM * BK];  // 128 KiB

    // Bijective XCD swizzle: each XCD owns 8 mblks x all 4 nblks.
    const int bid  = blockIdx.x;
    const int wgid = (bid & 7) * 32 + (bid >> 3);
    const int mblk = wgid >> 2;           // 0..63
    const int nblk = wgid & 3;            // 0..3

    const int t    = threadIdx.x;
    const int lane = t & 63;
    const int w    = t >> 6;
    const int wr   = w >> 2;              // 0..1  (M)
    const int wc   = w & 3;               // 0..3  (N)
    const int rr   = lane & 15;
    const int rq   = lane >> 4;
    const int sw   = (rr & 7) << 4;
    const int rqb  = rq * 16;
    const int wrb  = wr * 128;
    const int wcb  = wc * 64;

    const int arow = mblk * BM;
    const int brow = nblk * BN;

    f32x4 acc[8][4] = {};

    // ---- prologue: tile0 fully; tile1 B g0-3 + A g0,g1 --------------------
    {
#pragma unroll
        for (int g = 0; g < 4; ++g) stage_g(A,  arow, 0, g, &lds[0][0][0], t);
#pragma unroll
        for (int g = 0; g < 4; ++g) stage_g(Bm, brow, 0, g, &lds[0][1][0], t);
#pragma unroll
        for (int g = 0; g < 4; ++g) stage_g(Bm, brow, 1, g, &lds[1][1][0], t);
#pragma unroll
        for (int g = 0; g < 2; ++g) stage_g(A,  arow, 1, g, &lds[1][0][0], t);
        asm volatile("s_waitcnt vmcnt(6)" ::: "memory");   // tile0 landed
        asm volatile("" ::: "memory");
        __builtin_amdgcn_s_barrier();
    }

    bf16x8 af [4][2];   // A rows 0-63 of wave slab (current tile)
    bf16x8 af2[4][2];   // A rows 64-127 of wave slab
    bf16x8 bfr[4][2];   // all B fragments of current tile

    // pre-read tile0's ph0 operands (12 reads; drained by ph0's lgkmcnt(4))
#pragma unroll
    for (int m = 0; m < 4; ++m) {
        af[m][0] = ldsfrag(&lds[0][0][0], wrb + m * 16 + rr, (rqb) ^ sw);
        af[m][1] = ldsfrag(&lds[0][0][0], wrb + m * 16 + rr, (64 + rqb) ^ sw);
    }
#pragma unroll
    for (int n = 0; n < 2; ++n) {
        bfr[n][0] = ldsfrag(&lds[0][1][0], wcb + n * 16 + rr, (rqb) ^ sw);
        bfr[n][1] = ldsfrag(&lds[0][1][0], wcb + n * 16 + rr, (64 + rqb) ^ sw);
    }

    for (int kt = 0; kt < NT; ++kt) {
        const int c = kt & 1;
        const unsigned short* At = &lds[c][0][0];
        const unsigned short* Bt = &lds[c][1][0];
        const unsigned short* nxA = &lds[c ^ 1][0][0];  // tile kt+1
        const unsigned short* nxB = &lds[c ^ 1][1][0];
        unsigned short* curA = &lds[c][0][0];           // tile kt+2 targets
        unsigned short* curB = &lds[c][1][0];
        const bool pf1 = (kt + 1 < NT);
        const bool pf2 = (kt + 2 < NT);

        // -- ph0: issue bfr[2-3] (4 reads, feed ph1); stage A(kt+1) g2,g3 ---
#pragma unroll
        for (int n = 2; n < 4; ++n) {
            bfr[n][0] = ldsfrag(Bt, wcb + n * 16 + rr, (rqb) ^ sw);
            bfr[n][1] = ldsfrag(Bt, wcb + n * 16 + rr, (64 + rqb) ^ sw);
        }
        if (pf1) {
            stage_g(A, arow, kt + 1, 2, (unsigned short*)nxA, t);
            stage_g(A, arow, kt + 1, 3, (unsigned short*)nxA, t);
        }
        WAIT_PH(4);            // prev-phase reads (af/bfr[0-1]) complete
        MFMA_Q(af, 0, 0);      // m0-3 x n0-1
        BAR_OUT();

        // -- ph1: issue af2 (8 reads, feed ph2) -----------------------------
#pragma unroll
        for (int m = 0; m < 4; ++m) {
            af2[m][0] = ldsfrag(At, wrb + 64 + m * 16 + rr, (rqb) ^ sw);
            af2[m][1] = ldsfrag(At, wrb + 64 + m * 16 + rr, (64 + rqb) ^ sw);
        }
        WAIT_PH(8);            // ph0's bfr[2-3] complete
        MFMA_Q(af, 0, 2);      // m0-3 x n2-3
        BAR_OUT();

        // -- ph2: no reads; stage B(kt+2) g0,g1 -----------------------------
        if (pf2) {
            stage_g(Bm, brow, kt + 2, 0, curB, t);
            stage_g(Bm, brow, kt + 2, 1, curB, t);
        }
        WAIT_PH(0);            // ph1's af2 complete
        MFMA_Q(af2, 4, 0);     // m4-7 x n0-1
        __builtin_amdgcn_sched_barrier(0);
        // tile kt+1 readiness: drain everything except the 2 newest
        // (B(kt+2)g0,g1).  Tail: full drain at kt==NT-2.
        if (kt < NT - 2) {
            asm volatile("s_waitcnt vmcnt(2)" ::: "memory");
        } else if (kt == NT - 2) {
            asm volatile("s_waitcnt vmcnt(0)" ::: "memory");
        }
        asm volatile("" ::: "memory");
        __builtin_amdgcn_s_barrier();

        // -- ph3: pre-read tile kt+1's ph0 operands (12); stage B g2,g3 + A g0,g1
        if (pf1) {
#pragma unroll
            for (int m = 0; m < 4; ++m) {
                af[m][0] = ldsfrag(nxA, wrb + m * 16 + rr, (rqb) ^ sw);
                af[m][1] = ldsfrag(nxA, wrb + m * 16 + rr, (64 + rqb) ^ sw);
            }
#pragma unroll
            for (int n = 0; n < 2; ++n) {
                bfr[n][0] = ldsfrag(nxB, wcb + n * 16 + rr, (rqb) ^ sw);
                bfr[n][1] = ldsfrag(nxB, wcb + n * 16 + rr, (64 + rqb) ^ sw);
            }
        }
        if (pf2) {
            stage_g(Bm, brow, kt + 2, 2, curB, t);
            stage_g(Bm, brow, kt + 2, 3, curB, t);
            stage_g(A,  arow, kt + 2, 0, curA, t);
            stage_g(A,  arow, kt + 2, 1, curA, t);
        }
        if (pf1) { WAIT_PH(12); } else { WAIT_PH(0); }  // ph2 had 0 reads
        MFMA_Q(af2, 4, 2);     // m4-7 x n2-3
        BAR_OUT();
    }

    // ---- epilogue: C/D layout col=lane&15, row=(lane>>4)*4+j --------------
#pragma unroll
    for (int mi = 0; mi < 8; ++mi) {
#pragma unroll
        for (int n = 0; n < 4; ++n) {
            const int gcol = nblk * BN + wcb + n * 16 + rr;
#pragma unroll
            for (int j = 0; j < 4; ++j) {
                const int grow = mblk * BM + wrb + mi * 16 + rq * 4 + j;
                C[(size_t)grow * HIDDEN + gcol] = acc[mi][n][j];
            }
        }
    }
}

// ---------------------------------------------------------------------------
// In-place: p = C + MQ[idx[row]] + (W_b+U_b+Q_b); LayerNorm; sigmoid.
// ---------------------------------------------------------------------------
__global__ __launch_bounds__(256) void ln_kernel(
        float* __restrict__ C,
        const int* __restrict__ idxbuf,
        const float* __restrict__ MQ,
        const float* __restrict__ W_b, const float* __restrict__ U_b,
        const float* __restrict__ Q_b, const float* __restrict__ ln_g,
        const float* __restrict__ ln_b) {
    const int row = blockIdx.x;
    const int t   = threadIdx.x;
    const int midx = idxbuf[row];
    float4* rowp = reinterpret_cast<float4*>(C + (size_t)row * HIDDEN);
    const float4* mqp = reinterpret_cast<const float4*>(MQ + (size_t)midx * HIDDEN);

    float4 p  = rowp[t];
    float4 mq = mqp[t];
    float4 bw = reinterpret_cast<const float4*>(W_b)[t];
    float4 bu = reinterpret_cast<const float4*>(U_b)[t];
    float4 bq = reinterpret_cast<const float4*>(Q_b)[t];
    p.x += mq.x + bw.x + bu.x + bq.x;
    p.y += mq.y + bw.y + bu.y + bq.y;
    p.z += mq.z + bw.z + bu.z + bq.z;
    p.w += mq.w + bw.w + bu.w + bq.w;

    float s  = p.x + p.y + p.z + p.w;
    float sq = p.x * p.x + p.y * p.y + p.z * p.z + p.w * p.w;
#pragma unroll
    for (int off = 32; off >= 1; off >>= 1) {
        s  += __shfl_xor(s,  off, 64);
        sq += __shfl_xor(sq, off, 64);
    }
    __shared__ float red[8];
    const int lane = t & 63, w = t >> 6;
    if (lane == 0) { red[w] = s; red[4 + w] = sq; }
    __syncthreads();
    const float S    = red[0] + red[1] + red[2] + red[3];
    const float SQ   = red[4] + red[5] + red[6] + red[7];
    const float mean = S * (1.0f / HIDDEN);
    const float var  = SQ * (1.0f / HIDDEN) - mean * mean;
    const float rstd = rsqrtf(var + 1e-5f);

    float4 g = reinterpret_cast<const float4*>(ln_g)[t];
    float4 b = reinterpret_cast<const float4*>(ln_b)[t];
    float4 o;
    o.x = 1.f / (1.f + __expf(-((p.x - mean) * rstd * g.x + b.x)));
    o.y = 1.f / (1.f + __expf(-((p.y - mean) * rstd * g.y + b.y)));
    o.z = 1.f / (1.f + __expf(-((p.z - mean) * rstd * g.z + b.z)));
    o.w = 1.f / (1.f + __expf(-((p.w - mean) * rstd * g.w + b.w)));
    rowp[t] = o;
}

// ---------------------------------------------------------------------------
extern "C" void kernel_launch(void* const* d_in, const int* in_sizes, int n_in,
                              void* d_out, int out_size, void* d_ws, size_t ws_size,
                              hipStream_t stream) {
    const float* x      = (const float*)d_in[0];
    const float* h_prev = (const float*)d_in[1];
    const float* memory = (const float*)d_in[2];
    const float* W_w    = (const float*)d_in[3];
    const float* W_b    = (const float*)d_in[4];
    const float* U_w    = (const float*)d_in[5];
    const float* U_b    = (const float*)d_in[6];
    const float* Q_w    = (const float*)d_in[7];
    const float* Q_b    = (const float*)d_in[8];
    const float* M_w    = (const float*)d_in[9];
    const float* M_b    = (const float*)d_in[10];
    const float* ln_g   = (const float*)d_in[11];
    const float* ln_b   = (const float*)d_in[12];

    // ws layout (bytes):
    char* ws = (char*)d_ws;
    unsigned short* A   = (unsigned short*)(ws);                 // 67,108,864
    unsigned short* Bm  = (unsigned short*)(ws + 67108864);      //  4,194,304
    unsigned short* Mem = (unsigned short*)(ws + 71303168);      //  2,097,152
    unsigned short* Qb  = (unsigned short*)(ws + 73400320);      //  2,097,152
    float*          MQ  = (float*)         (ws + 75497472);      //  4,194,304
    int*            idx = (int*)           (ws + 79691776);      //     65,536
    float* pre = (float*)d_out;

    hipLaunchKernelGGL(pack_kernel, dim3(4096), dim3(256), 0, stream,
                       W_w, U_w, memory, Q_w, Bm, Mem, Qb);
    hipMemsetAsync(MQ, 0, (size_t)MEMSZ * HIDDEN * sizeof(float), stream);
    hipLaunchKernelGGL(mq_kernel, dim3(256), dim3(256), 0, stream,
                       Mem, Qb, MQ);
    hipLaunchKernelGGL(build_a_kernel, dim3(BATCH / 4), dim3(256), 0, stream,
                       x, h_prev, M_w, M_b, A, idx);
    hipLaunchKernelGGL(gemm_kernel, dim3((BATCH / BM) * (HIDDEN / BN)), dim3(512), 0, stream,
                       A, Bm, pre);
    hipLaunchKernelGGL(ln_kernel, dim3(BATCH), dim3(256), 0, stream,
                       pre, idx, MQ, W_b, U_b, Q_b, ln_g, ln_b);
}

// Round 7
// 166.646 us; speedup vs baseline: 1.2253x; 1.0211x over previous
//
#include <hip/hip_runtime.h>

#define BATCH   16384
#define HIDDEN  1024
#define K2      2048     // x | h_prev   (h_mem folded into MQ gather)
#define MEMSZ   1024
#define NBITS   10

#define BM 256
#define BN 256
#define BK 64
#define NT (K2 / BK)     // 32 K-tiles

typedef __bf16 bf16x8 __attribute__((ext_vector_type(8)));
typedef float  f32x4  __attribute__((ext_vector_type(4)));

__device__ __forceinline__ unsigned short f2bf(float f) {
    unsigned int u = __float_as_uint(f);
    u += 0x7FFFu + ((u >> 16) & 1u);   // round-to-nearest-even
    return (unsigned short)(u >> 16);
}

__device__ __forceinline__ void gload_lds16(const void* g, void* l) {
    __builtin_amdgcn_global_load_lds(
        (const __attribute__((address_space(1))) unsigned int*)g,
        (__attribute__((address_space(3))) unsigned int*)l,
        16, 0, 0);
}

// ---------------------------------------------------------------------------
// Merged pack + build_a (independent work, one launch):
//  blocks 0..4095:    Bm[1024][2048]=bf16([W|U]); Mem=bf16(memory); Qb=bf16(Q)
//  blocks 4096..8191: per-row fp32 logits -> idx; A[row][2048]=bf16([x|h])
// ---------------------------------------------------------------------------
__global__ __launch_bounds__(256) void pack_build_kernel(
        const float* __restrict__ W, const float* __restrict__ U,
        const float* __restrict__ memory, const float* __restrict__ Q,
        const float* __restrict__ x, const float* __restrict__ h_prev,
        const float* __restrict__ M_w, const float* __restrict__ M_b,
        unsigned short* __restrict__ Bm, unsigned short* __restrict__ Mem,
        unsigned short* __restrict__ Qb, unsigned short* __restrict__ A,
        int* __restrict__ idxbuf) {
    if (blockIdx.x < 4096) {
        int u = blockIdx.x * 256 + threadIdx.x;
        const float* src;
        unsigned short* dst;
        if (u < 524288) {                       // Bm
            int n = u >> 9;
            int k = (u & 511) * 4;
            src = (k < 1024) ? (W + (size_t)n * 1024 + k)
                             : (U + (size_t)n * 1024 + (k - 1024));
            dst = Bm + (size_t)n * K2 + k;
        } else if (u < 786432) {                // Mem_bf16
            int f = (u - 524288) * 4;
            src = memory + f;  dst = Mem + f;
        } else {                                // Q_bf16
            int f = (u - 786432) * 4;
            src = Q + f;  dst = Qb + f;
        }
        float4 v = *reinterpret_cast<const float4*>(src);
        ushort4 o;
        o.x = f2bf(v.x); o.y = f2bf(v.y); o.z = f2bf(v.z); o.w = f2bf(v.w);
        *reinterpret_cast<ushort4*>(dst) = o;
        return;
    }

    int row  = ((blockIdx.x - 4096) * 256 + threadIdx.x) >> 6;
    int lane = threadIdx.x & 63;
    if (row >= BATCH) return;

    const float4* hp = reinterpret_cast<const float4*>(h_prev + (size_t)row * HIDDEN);
    float4 hv[4];
#pragma unroll
    for (int i = 0; i < 4; ++i) hv[i] = hp[i * 64 + lane];

    int idx = 0;
#pragma unroll
    for (int j = 0; j < NBITS; ++j) {
        const float4* mp = reinterpret_cast<const float4*>(M_w + (size_t)j * HIDDEN);
        float s = 0.f;
#pragma unroll
        for (int i = 0; i < 4; ++i) {
            float4 m = mp[i * 64 + lane];
            s += hv[i].x * m.x + hv[i].y * m.y + hv[i].z * m.z + hv[i].w * m.w;
        }
#pragma unroll
        for (int off = 32; off >= 1; off >>= 1) s += __shfl_xor(s, off, 64);
        float logit = s + M_b[j];
        if (logit > 0.f) idx |= (1 << (NBITS - 1 - j));
    }
    if (lane == 0) idxbuf[row] = idx;

    unsigned short* arow = A + (size_t)row * K2;
    const float4* xp = reinterpret_cast<const float4*>(x + (size_t)row * HIDDEN);
#pragma unroll
    for (int i = 0; i < 4; ++i) {
        int off = i * 256 + lane * 4;
        float4 vx = xp[i * 64 + lane];
        ushort4 ox; ox.x = f2bf(vx.x); ox.y = f2bf(vx.y); ox.z = f2bf(vx.z); ox.w = f2bf(vx.w);
        *reinterpret_cast<ushort4*>(arow + off) = ox;

        ushort4 oh; oh.x = f2bf(hv[i].x); oh.y = f2bf(hv[i].y); oh.z = f2bf(hv[i].z); oh.w = f2bf(hv[i].w);
        *reinterpret_cast<ushort4*>(arow + 1024 + off) = oh;
    }
}

// ---------------------------------------------------------------------------
// MQ[1024][1024] f32 = Mem_bf16 @ Qb^T, split-K x4, atomicAdd epilogue.
// ---------------------------------------------------------------------------
__global__ __launch_bounds__(256) void mq_kernel(
        const unsigned short* __restrict__ Mem,
        const unsigned short* __restrict__ Qb,
        float* __restrict__ MQ) {
    __shared__ unsigned short As[128 * 64];
    __shared__ unsigned short Bs[128 * 64];

    const int ks = blockIdx.x >> 6;
    const int mb = (blockIdx.x >> 3) & 7;
    const int nb = blockIdx.x & 7;
    const int t    = threadIdx.x;
    const int lane = t & 63;
    const int w    = t >> 6;
    const int wr   = w >> 1, wc = w & 1;
    const int rr   = lane & 15, rq = lane >> 4;
    const int c8   = (t & 7) * 8;
    const int srow = t >> 3;

    f32x4 acc[4][4] = {};

    for (int kt = 0; kt < 4; ++kt) {
        const int k0 = ks * 256 + kt * 64;
#pragma unroll
        for (int i = 0; i < 4; ++i) {
            int r = i * 32 + srow;
            gload_lds16(Mem + (size_t)(mb * 128 + r) * 1024 + k0 + c8, As + i * 2048 + t * 8);
            gload_lds16(Qb  + (size_t)(nb * 128 + r) * 1024 + k0 + c8, Bs + i * 2048 + t * 8);
        }
        __syncthreads();
#pragma unroll
        for (int kk = 0; kk < 2; ++kk) {
            const int krd = kk * 32 + rq * 8;
            bf16x8 af[4], bfv[4];
#pragma unroll
            for (int m = 0; m < 4; ++m)
                af[m] = *reinterpret_cast<const bf16x8*>(As + (wr * 64 + m * 16 + rr) * 64 + krd);
#pragma unroll
            for (int n = 0; n < 4; ++n)
                bfv[n] = *reinterpret_cast<const bf16x8*>(Bs + (wc * 64 + n * 16 + rr) * 64 + krd);
#pragma unroll
            for (int m = 0; m < 4; ++m)
#pragma unroll
                for (int n = 0; n < 4; ++n)
                    acc[m][n] = __builtin_amdgcn_mfma_f32_16x16x32_bf16(
                        af[m], bfv[n], acc[m][n], 0, 0, 0);
        }
        __syncthreads();
    }

#pragma unroll
    for (int m = 0; m < 4; ++m)
#pragma unroll
        for (int n = 0; n < 4; ++n) {
            int gcol = nb * 128 + wc * 64 + n * 16 + rr;
#pragma unroll
            for (int j = 0; j < 4; ++j) {
                int grow = mb * 128 + wr * 64 + m * 16 + rq * 4 + j;
                atomicAdd(&MQ[(size_t)grow * 1024 + gcol], acc[m][n][j]);
            }
        }
}

// ---------------------------------------------------------------------------
// 256x256-tile GEMM, rotated + BALANCED: exactly 6 ds_read_b128 per wave per
// phase (48/CU = 576 cy <= 620 cy MFMA window), one-phase-ahead feeding,
// counted lgkmcnt; stages B(kt+2)x4 @ph2, A(kt+2)x4 @ph3; vmcnt(0) @ph1-end
// (drains only 2-3-phase-old stages).
//   ph0: Q(0,0) af*b01   | issue b23(4),af2[0](2)       WAIT lgkm(6)
//   ph1: Q(0,2) af*b23   | issue af2[1-3](6)            WAIT lgkm(8)
//   ph2: Q(4,0) af2*b01  | issue af(kt+1)[0-2](6)       WAIT lgkm(6)
//   ph3: Q(4,2) af2*b23  | issue af(kt+1)[3]+b01(kt+1)  WAIT lgkm(12)
// ---------------------------------------------------------------------------

__device__ __forceinline__ void stage_g(const unsigned short* __restrict__ src,
                                        int rowbase, int kt, int g,
                                        unsigned short* ldsTile, int t) {
    const int o      = g * 8192 + t * 16;     // byte offset within 32 KB tile
    const int row    = o >> 7;                // 0..255  (128 B per row)
    const int inner  = o & 127;
    const int sinner = inner ^ ((row & 7) << 4);
    const char* gp = reinterpret_cast<const char*>(
                         src + (size_t)(rowbase + row) * K2 + kt * BK) + sinner;
    gload_lds16(gp, reinterpret_cast<char*>(ldsTile) + o);
}

__device__ __forceinline__ bf16x8 ldsfrag(const unsigned short* tile, int row,
                                          int kbyte_x_sw) {
    return *reinterpret_cast<const bf16x8*>(
        reinterpret_cast<const char*>(tile) + row * 128 + kbyte_x_sw);
}

#define WAIT_PH(N)                                                   \
    do {                                                             \
        asm volatile("" ::: "memory");                               \
        __builtin_amdgcn_s_barrier();                                \
        asm volatile("s_waitcnt lgkmcnt(" #N ")" ::: "memory");      \
        __builtin_amdgcn_sched_barrier(0);                           \
    } while (0)

#define BAR_OUT()                                                    \
    do {                                                             \
        __builtin_amdgcn_sched_barrier(0);                           \
        asm volatile("" ::: "memory");                               \
        __builtin_amdgcn_s_barrier();                                \
    } while (0)

// One C-quadrant x K=64: 16 MFMAs, setprio-wrapped (T5).
#define MFMA_Q(AF, BF, MB, NB)                                                 \
    {                                                                          \
        __builtin_amdgcn_s_setprio(1);                                         \
        _Pragma("unroll") for (int m_ = 0; m_ < 4; ++m_)                       \
        _Pragma("unroll") for (int n_ = 0; n_ < 2; ++n_)                       \
        _Pragma("unroll") for (int kk_ = 0; kk_ < 2; ++kk_)                    \
            acc[(MB) + m_][(NB) + n_] =                                        \
                __builtin_amdgcn_mfma_f32_16x16x32_bf16(                       \
                    AF[m_][kk_], BF[n_][kk_],                                  \
                    acc[(MB) + m_][(NB) + n_], 0, 0, 0);                       \
        __builtin_amdgcn_s_setprio(0);                                         \
    }

__global__ __launch_bounds__(512, 2) void gemm_kernel(
        const unsigned short* __restrict__ A,
        const unsigned short* __restrict__ Bm,
        float* __restrict__ C) {
    __shared__ alignas(16) unsigned short lds[2][2][BM * BK];  // 128 KiB

    // Bijective XCD swizzle: each XCD owns 8 mblks x all 4 nblks.
    const int bid  = blockIdx.x;
    const int wgid = (bid & 7) * 32 + (bid >> 3);
    const int mblk = wgid >> 2;           // 0..63
    const int nblk = wgid & 3;            // 0..3

    const int t    = threadIdx.x;
    const int lane = t & 63;
    const int w    = t >> 6;
    const int wr   = w >> 2;              // 0..1  (M)
    const int wc   = w & 3;               // 0..3  (N)
    const int rr   = lane & 15;
    const int rq   = lane >> 4;
    const int sw   = (rr & 7) << 4;
    const int rqb  = rq * 16;
    const int wrb  = wr * 128;
    const int wcb  = wc * 64;

    const int arow = mblk * BM;
    const int brow = nblk * BN;

    f32x4 acc[8][4] = {};

    // ---- prologue: stage tile0 (A,B) + tile1 (B,A); drain tile0 -----------
    {
#pragma unroll
        for (int g = 0; g < 4; ++g) stage_g(A,  arow, 0, g, &lds[0][0][0], t);
#pragma unroll
        for (int g = 0; g < 4; ++g) stage_g(Bm, brow, 0, g, &lds[0][1][0], t);
#pragma unroll
        for (int g = 0; g < 4; ++g) stage_g(Bm, brow, 1, g, &lds[1][1][0], t);
#pragma unroll
        for (int g = 0; g < 4; ++g) stage_g(A,  arow, 1, g, &lds[1][0][0], t);
        asm volatile("s_waitcnt vmcnt(8)" ::: "memory");   // tile0 landed
        asm volatile("" ::: "memory");
        __builtin_amdgcn_s_barrier();
    }

    bf16x8 af  [4][2];   // A rows 0-63 of wave slab
    bf16x8 af2 [4][2];   // A rows 64-127 of wave slab
    bf16x8 bfr01[2][2];  // B cols wcb+0..31
    bf16x8 bfr23[2][2];  // B cols wcb+32..63

    // pre-issue iter0 ph0 feeds: af(0) (8) + b01(0) (4)
#pragma unroll
    for (int m = 0; m < 4; ++m) {
        af[m][0] = ldsfrag(&lds[0][0][0], wrb + m * 16 + rr, (rqb) ^ sw);
        af[m][1] = ldsfrag(&lds[0][0][0], wrb + m * 16 + rr, (64 + rqb) ^ sw);
    }
#pragma unroll
    for (int n = 0; n < 2; ++n) {
        bfr01[n][0] = ldsfrag(&lds[0][1][0], wcb + n * 16 + rr, (rqb) ^ sw);
        bfr01[n][1] = ldsfrag(&lds[0][1][0], wcb + n * 16 + rr, (64 + rqb) ^ sw);
    }
    __builtin_amdgcn_sched_barrier(0);   // pin issue order vs loop ph0 reads

    for (int kt = 0; kt < NT; ++kt) {
        const int c = kt & 1;
        const unsigned short* At  = &lds[c][0][0];
        const unsigned short* Bt  = &lds[c][1][0];
        const unsigned short* nxA = &lds[c ^ 1][0][0];  // tile kt+1
        const unsigned short* nxB = &lds[c ^ 1][1][0];
        unsigned short* curA = &lds[c][0][0];           // tile kt+2 targets
        unsigned short* curB = &lds[c][1][0];
        const bool pf1 = (kt + 1 < NT);
        const bool pf2 = (kt + 2 < NT);

        // -- ph0: issue b23 (4) then af2[0] (2) -----------------------------
#pragma unroll
        for (int n = 0; n < 2; ++n) {
            bfr23[n][0] = ldsfrag(Bt, wcb + 32 + n * 16 + rr, (rqb) ^ sw);
            bfr23[n][1] = ldsfrag(Bt, wcb + 32 + n * 16 + rr, (64 + rqb) ^ sw);
        }
        __builtin_amdgcn_sched_barrier(0);   // b23 strictly before af2[0]
        af2[0][0] = ldsfrag(At, wrb + 64 + rr, (rqb) ^ sw);
        af2[0][1] = ldsfrag(At, wrb + 64 + rr, (64 + rqb) ^ sw);
        WAIT_PH(6);            // drains af+b01 (prev ph2/ph3)
        MFMA_Q(af, bfr01, 0, 0);
        BAR_OUT();

        // -- ph1: issue af2[1-3] (6) ---------------------------------------
#pragma unroll
        for (int m = 1; m < 4; ++m) {
            af2[m][0] = ldsfrag(At, wrb + 64 + m * 16 + rr, (rqb) ^ sw);
            af2[m][1] = ldsfrag(At, wrb + 64 + m * 16 + rr, (64 + rqb) ^ sw);
        }
        WAIT_PH(8);            // drains b23 (leaves af2[0] + ph1's 6)
        MFMA_Q(af, bfr23, 0, 2);
        __builtin_amdgcn_sched_barrier(0);
        // tile kt+1 fully staged: newest outstanding stages are 2-3 phases old
        asm volatile("s_waitcnt vmcnt(0)" ::: "memory");
        asm volatile("" ::: "memory");
        __builtin_amdgcn_s_barrier();

        // -- ph2: stage B(kt+2) x4; issue af(kt+1)[0-2] (6) -----------------
        if (pf2) {
            stage_g(Bm, brow, kt + 2, 0, curB, t);
            stage_g(Bm, brow, kt + 2, 1, curB, t);
            stage_g(Bm, brow, kt + 2, 2, curB, t);
            stage_g(Bm, brow, kt + 2, 3, curB, t);
        }
        if (pf1) {
#pragma unroll
            for (int m = 0; m < 3; ++m) {
                af[m][0] = ldsfrag(nxA, wrb + m * 16 + rr, (rqb) ^ sw);
                af[m][1] = ldsfrag(nxA, wrb + m * 16 + rr, (64 + rqb) ^ sw);
            }
            WAIT_PH(6);        // drains af2[0-3] (leaves ph2's 6)
        } else {
            WAIT_PH(0);        // tail: drain af2 fully
        }
        MFMA_Q(af2, bfr01, 4, 0);
        BAR_OUT();

        // -- ph3: stage A(kt+2) x4; issue af(kt+1)[3] (2) + b01(kt+1) (4) ---
        if (pf2) {
            stage_g(A, arow, kt + 2, 0, curA, t);
            stage_g(A, arow, kt + 2, 1, curA, t);
            stage_g(A, arow, kt + 2, 2, curA, t);
            stage_g(A, arow, kt + 2, 3, curA, t);
        }
        if (pf1) {
            af[3][0] = ldsfrag(nxA, wrb + 48 + rr, (rqb) ^ sw);
            af[3][1] = ldsfrag(nxA, wrb + 48 + rr, (64 + rqb) ^ sw);
#pragma unroll
            for (int n = 0; n < 2; ++n) {
                bfr01[n][0] = ldsfrag(nxB, wcb + n * 16 + rr, (rqb) ^ sw);
                bfr01[n][1] = ldsfrag(nxB, wcb + n * 16 + rr, (64 + rqb) ^ sw);
            }
        }
        WAIT_PH(12);           // no new deps (af2/b23 already drained)
        MFMA_Q(af2, bfr23, 4, 2);
        BAR_OUT();
    }

    // ---- epilogue: C/D layout col=lane&15, row=(lane>>4)*4+j --------------
#pragma unroll
    for (int mi = 0; mi < 8; ++mi) {
#pragma unroll
        for (int n = 0; n < 4; ++n) {
            const int gcol = nblk * BN + wcb + n * 16 + rr;
#pragma unroll
            for (int j = 0; j < 4; ++j) {
                const int grow = mblk * BM + wrb + mi * 16 + rq * 4 + j;
                C[(size_t)grow * HIDDEN + gcol] = acc[mi][n][j];
            }
        }
    }
}

// ---------------------------------------------------------------------------
// In-place: p = C + MQ[idx[row]] + (W_b+U_b+Q_b); LayerNorm; sigmoid.
// ---------------------------------------------------------------------------
__global__ __launch_bounds__(256) void ln_kernel(
        float* __restrict__ C,
        const int* __restrict__ idxbuf,
        const float* __restrict__ MQ,
        const float* __restrict__ W_b, const float* __restrict__ U_b,
        const float* __restrict__ Q_b, const float* __restrict__ ln_g,
        const float* __restrict__ ln_b) {
    const int row = blockIdx.x;
    const int t   = threadIdx.x;
    const int midx = idxbuf[row];
    float4* rowp = reinterpret_cast<float4*>(C + (size_t)row * HIDDEN);
    const float4* mqp = reinterpret_cast<const float4*>(MQ + (size_t)midx * HIDDEN);

    float4 p  = rowp[t];
    float4 mq = mqp[t];
    float4 bw = reinterpret_cast<const float4*>(W_b)[t];
    float4 bu = reinterpret_cast<const float4*>(U_b)[t];
    float4 bq = reinterpret_cast<const float4*>(Q_b)[t];
    p.x += mq.x + bw.x + bu.x + bq.x;
    p.y += mq.y + bw.y + bu.y + bq.y;
    p.z += mq.z + bw.z + bu.z + bq.z;
    p.w += mq.w + bw.w + bu.w + bq.w;

    float s  = p.x + p.y + p.z + p.w;
    float sq = p.x * p.x + p.y * p.y + p.z * p.z + p.w * p.w;
#pragma unroll
    for (int off = 32; off >= 1; off >>= 1) {
        s  += __shfl_xor(s,  off, 64);
        sq += __shfl_xor(sq, off, 64);
    }
    __shared__ float red[8];
    const int lane = t & 63, w = t >> 6;
    if (lane == 0) { red[w] = s; red[4 + w] = sq; }
    __syncthreads();
    const float S    = red[0] + red[1] + red[2] + red[3];
    const float SQ   = red[4] + red[5] + red[6] + red[7];
    const float mean = S * (1.0f / HIDDEN);
    const float var  = SQ * (1.0f / HIDDEN) - mean * mean;
    const float rstd = rsqrtf(var + 1e-5f);

    float4 g = reinterpret_cast<const float4*>(ln_g)[t];
    float4 b = reinterpret_cast<const float4*>(ln_b)[t];
    float4 o;
    o.x = 1.f / (1.f + __expf(-((p.x - mean) * rstd * g.x + b.x)));
    o.y = 1.f / (1.f + __expf(-((p.y - mean) * rstd * g.y + b.y)));
    o.z = 1.f / (1.f + __expf(-((p.z - mean) * rstd * g.z + b.z)));
    o.w = 1.f / (1.f + __expf(-((p.w - mean) * rstd * g.w + b.w)));
    rowp[t] = o;
}

// ---------------------------------------------------------------------------
extern "C" void kernel_launch(void* const* d_in, const int* in_sizes, int n_in,
                              void* d_out, int out_size, void* d_ws, size_t ws_size,
                              hipStream_t stream) {
    const float* x      = (const float*)d_in[0];
    const float* h_prev = (const float*)d_in[1];
    const float* memory = (const float*)d_in[2];
    const float* W_w    = (const float*)d_in[3];
    const float* W_b    = (const float*)d_in[4];
    const float* U_w    = (const float*)d_in[5];
    const float* U_b    = (const float*)d_in[6];
    const float* Q_w    = (const float*)d_in[7];
    const float* Q_b    = (const float*)d_in[8];
    const float* M_w    = (const float*)d_in[9];
    const float* M_b    = (const float*)d_in[10];
    const float* ln_g   = (const float*)d_in[11];
    const float* ln_b   = (const float*)d_in[12];

    // ws layout (bytes):
    char* ws = (char*)d_ws;
    unsigned short* A   = (unsigned short*)(ws);                 // 67,108,864
    unsigned short* Bm  = (unsigned short*)(ws + 67108864);      //  4,194,304
    unsigned short* Mem = (unsigned short*)(ws + 71303168);      //  2,097,152
    unsigned short* Qb  = (unsigned short*)(ws + 73400320);      //  2,097,152
    float*          MQ  = (float*)         (ws + 75497472);      //  4,194,304
    int*            idx = (int*)           (ws + 79691776);      //     65,536
    float* pre = (float*)d_out;

    hipLaunchKernelGGL(pack_build_kernel, dim3(8192), dim3(256), 0, stream,
                       W_w, U_w, memory, Q_w, x, h_prev, M_w, M_b,
                       Bm, Mem, Qb, A, idx);
    hipMemsetAsync(MQ, 0, (size_t)MEMSZ * HIDDEN * sizeof(float), stream);
    hipLaunchKernelGGL(mq_kernel, dim3(256), dim3(256), 0, stream,
                       Mem, Qb, MQ);
    hipLaunchKernelGGL(gemm_kernel, dim3((BATCH / BM) * (HIDDEN / BN)), dim3(512), 0, stream,
                       A, Bm, pre);
    hipLaunchKernelGGL(ln_kernel, dim3(BATCH), dim3(256), 0, stream,
                       pre, idx, MQ, W_b, U_b, Q_b, ln_g, ln_b);
}